// Round 1
// baseline (6243.282 us; speedup 1.0000x reference)
//
#include <hip/hip_runtime.h>

#define LAYERS 8
#define SEQ 256
#define BATCH 64
#define HID 512
#define G4 2048   // 4*HID, pytorch gate order i,f,g,o
#define NSENS 64
#define NSTAGES (SEQ + LAYERS - 1)  // 263

typedef _Float16 h16;
typedef h16 h16x8 __attribute__((ext_vector_type(8)));
typedef float f32x4 __attribute__((ext_vector_type(4)));

// ---- workspace layout (bytes) ----
#define WHH_ELEMS   (LAYERS * G4 * HID)            // 8388608
#define WIHR_ELEMS  ((LAYERS - 1) * G4 * HID)      // 7340032
#define WIH0_ELEMS  (G4 * NSENS)                   // 131072
#define WF16_BYTES  ((WHH_ELEMS + WIHR_ELEMS + WIH0_ELEMS) * 2)  // 31719424
#define BIASC_OFF   (WF16_BYTES)                                 // fp32 [L][G4]
#define XT_OFF      (BIASC_OFF + LAYERS * G4 * 4)                // h16 [T][B][NSENS]
#define HBUF_OFF    (XT_OFF + SEQ * BATCH * NSENS * 2)           // h16 [2][L][B][H]
#define CBUF_OFF    (HBUF_OFF + 2 * LAYERS * BATCH * HID * 2)    // fp32 [L][B][H]
#define H7_OFF      (CBUF_OFF + LAYERS * BATCH * HID * 4)        // fp32 [B][H]

// ---------------- prep: convert weights/x to fp16, combine bias, zero state ----------------
__global__ void prep_kernel(const float* __restrict__ x,
                            const float* __restrict__ Wih0,
                            const float* __restrict__ WihR,
                            const float* __restrict__ Whh,
                            const float* __restrict__ bih,
                            const float* __restrict__ bhh,
                            h16* __restrict__ wf16,
                            float* __restrict__ biasc,
                            h16* __restrict__ xT,
                            h16* __restrict__ hbuf,
                            float* __restrict__ cbuf) {
  const int tid = blockIdx.x * blockDim.x + threadIdx.x;
  const int nt = gridDim.x * blockDim.x;
  for (int i = tid; i < WHH_ELEMS; i += nt) wf16[i] = (h16)Whh[i];
  for (int i = tid; i < WIHR_ELEMS; i += nt) wf16[WHH_ELEMS + i] = (h16)WihR[i];
  for (int i = tid; i < WIH0_ELEMS; i += nt) wf16[WHH_ELEMS + WIHR_ELEMS + i] = (h16)Wih0[i];
  for (int i = tid; i < LAYERS * G4; i += nt) biasc[i] = bih[i] + bhh[i];
  // x: [B][T][NSENS] -> xT: [T][B][NSENS] fp16
  for (int i = tid; i < SEQ * BATCH * NSENS; i += nt) {
    int t = i / (BATCH * NSENS);
    int r = i - t * (BATCH * NSENS);
    int b = r / NSENS;
    int s2 = r - b * NSENS;
    xT[i] = (h16)x[(b * SEQ + t) * NSENS + s2];
  }
  for (int i = tid; i < 2 * LAYERS * BATCH * HID; i += nt) hbuf[i] = (h16)0.f;
  for (int i = tid; i < LAYERS * BATCH * HID; i += nt) cbuf[i] = 0.f;
}

// ---------------- one pipeline stage: every active layer advances one timestep ----------------
// WG w: layer = w>>5, slice = w&31 (16 hidden units -> 64 gate rows, 16 per gate).
// wave = gate index (i,f,g,o). Each wave: D tile [M=64 batch, N=16 gate rows],
// K = 512 (recurrent) + 512/64 (input proj), via mfma_f32_16x16x32_f16.
__global__ __launch_bounds__(256) void stage_kernel(
    const h16* __restrict__ wf16, const float* __restrict__ biasc,
    const h16* __restrict__ xT, h16* __restrict__ hbuf,
    float* __restrict__ cbuf, float* __restrict__ h7, int s) {
  const int wg = blockIdx.x;
  const int l = wg >> 5;
  const int slice = wg & 31;
  const int t = s - 1 - l;
  if (t < 0 || t >= SEQ) return;

  const int tid = threadIdx.x;
  const int wave = tid >> 6;   // 0..3 = gate
  const int lane = tid & 63;
  const int nlo = lane & 15;   // n (B-frag) / m (A-frag) within tile
  const int quad = lane >> 4;  // k-group

  const int par_r = (s - 1) & 1;  // read parity
  const int par_w = s & 1;        // write parity

  const h16* Whh = wf16 + (size_t)l * G4 * HID;
  const h16* hprev = hbuf + ((size_t)par_r * LAYERS + l) * BATCH * HID;  // own h at t-1
  const h16* xin;
  const h16* Wih;
  int kx;
  if (l == 0) {
    xin = xT + (size_t)t * BATCH * NSENS;
    Wih = wf16 + WHH_ELEMS + WIHR_ELEMS;
    kx = NSENS;
  } else {
    xin = hbuf + ((size_t)par_r * LAYERS + (l - 1)) * BATCH * HID;  // h_{l-1} at t
    Wih = wf16 + WHH_ELEMS + (size_t)(l - 1) * G4 * HID;
    kx = HID;
  }

  const int ng = wave * HID + slice * 16;  // gate-row base for this wave

  f32x4 acc0 = {0.f, 0.f, 0.f, 0.f};
  f32x4 acc1 = {0.f, 0.f, 0.f, 0.f};
  f32x4 acc2 = {0.f, 0.f, 0.f, 0.f};
  f32x4 acc3 = {0.f, 0.f, 0.f, 0.f};

  // ---- recurrent GEMM: gates += h_{t-1} @ Whh^T (K = 512) ----
  {
    const h16* wrow = Whh + (size_t)(ng + nlo) * HID + quad * 8;
    const h16* arow = hprev + (size_t)nlo * HID + quad * 8;
#pragma unroll
    for (int kt = 0; kt < HID / 32; ++kt) {
      h16x8 bf = *(const h16x8*)(wrow + kt * 32);
      h16x8 a0 = *(const h16x8*)(arow + kt * 32);
      h16x8 a1 = *(const h16x8*)(arow + 16 * HID + kt * 32);
      h16x8 a2 = *(const h16x8*)(arow + 32 * HID + kt * 32);
      h16x8 a3 = *(const h16x8*)(arow + 48 * HID + kt * 32);
      acc0 = __builtin_amdgcn_mfma_f32_16x16x32_f16(a0, bf, acc0, 0, 0, 0);
      acc1 = __builtin_amdgcn_mfma_f32_16x16x32_f16(a1, bf, acc1, 0, 0, 0);
      acc2 = __builtin_amdgcn_mfma_f32_16x16x32_f16(a2, bf, acc2, 0, 0, 0);
      acc3 = __builtin_amdgcn_mfma_f32_16x16x32_f16(a3, bf, acc3, 0, 0, 0);
    }
  }
  // ---- input projection GEMM: gates += x_t @ Wih^T (K = kx) ----
  {
    const h16* wrow = Wih + (size_t)(ng + nlo) * kx + quad * 8;
    const h16* arow = xin + (size_t)nlo * kx + quad * 8;
    const int nkt = kx >> 5;
#pragma unroll 4
    for (int kt = 0; kt < nkt; ++kt) {
      h16x8 bf = *(const h16x8*)(wrow + kt * 32);
      h16x8 a0 = *(const h16x8*)(arow + kt * 32);
      h16x8 a1 = *(const h16x8*)(arow + (size_t)16 * kx + kt * 32);
      h16x8 a2 = *(const h16x8*)(arow + (size_t)32 * kx + kt * 32);
      h16x8 a3 = *(const h16x8*)(arow + (size_t)48 * kx + kt * 32);
      acc0 = __builtin_amdgcn_mfma_f32_16x16x32_f16(a0, bf, acc0, 0, 0, 0);
      acc1 = __builtin_amdgcn_mfma_f32_16x16x32_f16(a1, bf, acc1, 0, 0, 0);
      acc2 = __builtin_amdgcn_mfma_f32_16x16x32_f16(a2, bf, acc2, 0, 0, 0);
      acc3 = __builtin_amdgcn_mfma_f32_16x16x32_f16(a3, bf, acc3, 0, 0, 0);
    }
  }

  // ---- exchange gates across waves, apply LSTM cell ----
  __shared__ float gbuf[4][BATCH][16];
  const float bval = biasc[l * G4 + ng + nlo];
  // C/D layout: col n = lane&15, row m = quad*4 + reg (+ 16*mtile)
#pragma unroll
  for (int reg = 0; reg < 4; ++reg) {
    gbuf[wave][quad * 4 + reg + 0][nlo] = acc0[reg] + bval;
    gbuf[wave][quad * 4 + reg + 16][nlo] = acc1[reg] + bval;
    gbuf[wave][quad * 4 + reg + 32][nlo] = acc2[reg] + bval;
    gbuf[wave][quad * 4 + reg + 48][nlo] = acc3[reg] + bval;
  }
  __syncthreads();

  h16* hout = hbuf + ((size_t)par_w * LAYERS + l) * BATCH * HID;
  float* cb = cbuf + (size_t)l * BATCH * HID;
#pragma unroll
  for (int idx = tid; idx < BATCH * 16; idx += 256) {
    int b = idx >> 4;
    int j = idx & 15;
    float iv = gbuf[0][b][j];
    float fv = gbuf[1][b][j];
    float gv = gbuf[2][b][j];
    float ov = gbuf[3][b][j];
    iv = 1.f / (1.f + expf(-iv));
    fv = 1.f / (1.f + expf(-fv));
    gv = tanhf(gv);
    ov = 1.f / (1.f + expf(-ov));
    int jj = slice * 16 + j;
    float cold = cb[(size_t)b * HID + jj];
    float cnew = fv * cold + iv * gv;
    cb[(size_t)b * HID + jj] = cnew;
    float hv = ov * tanhf(cnew);
    hout[(size_t)b * HID + jj] = (h16)hv;
    if (l == LAYERS - 1) h7[(size_t)b * HID + jj] = hv;
  }
}

// ---------------- head: out = h7 @ Wlin^T + blin ----------------
__global__ void final_kernel(const float* __restrict__ h7,
                             const float* __restrict__ Wlin,
                             const float* __restrict__ blin,
                             float* __restrict__ out) {
  int tid = threadIdx.x;
  if (tid < BATCH * 2) {
    int b = tid >> 1;
    int o = tid & 1;
    float s = 0.f;
    for (int j = 0; j < HID; ++j) s += h7[(size_t)b * HID + j] * Wlin[o * HID + j];
    out[b * 2 + o] = s + blin[o];
  }
}

extern "C" void kernel_launch(void* const* d_in, const int* in_sizes, int n_in,
                              void* d_out, int out_size, void* d_ws, size_t ws_size,
                              hipStream_t stream) {
  (void)in_sizes; (void)n_in; (void)out_size; (void)ws_size;
  const float* x    = (const float*)d_in[0];
  const float* Wih0 = (const float*)d_in[1];
  const float* WihR = (const float*)d_in[2];
  const float* Whh  = (const float*)d_in[3];
  const float* bih  = (const float*)d_in[4];
  const float* bhh  = (const float*)d_in[5];
  const float* Wlin = (const float*)d_in[6];
  const float* blin = (const float*)d_in[7];
  float* out = (float*)d_out;

  char* ws = (char*)d_ws;
  h16* wf16    = (h16*)(ws);
  float* biasc = (float*)(ws + BIASC_OFF);
  h16* xT      = (h16*)(ws + XT_OFF);
  h16* hbuf    = (h16*)(ws + HBUF_OFF);
  float* cbuf  = (float*)(ws + CBUF_OFF);
  float* h7    = (float*)(ws + H7_OFF);

  prep_kernel<<<512, 256, 0, stream>>>(x, Wih0, WihR, Whh, bih, bhh,
                                       wf16, biasc, xT, hbuf, cbuf);
  for (int s = 1; s <= NSTAGES; ++s) {
    stage_kernel<<<256, 256, 0, stream>>>(wf16, biasc, xT, hbuf, cbuf, h7, s);
  }
  final_kernel<<<1, 128, 0, stream>>>(h7, Wlin, blin, out);
}